// Round 9
// baseline (428.989 us; speedup 1.0000x reference)
//
#include <hip/hip_runtime.h>
#include <hip/hip_fp16.h>
#include <math.h>

#define N_NODES 100000
#define N_RELS  3
#define N_EDGES 400000
#define D       128
#define NTOT    (N_RELS * N_NODES)   // 300000
#define ELL_W   12
#define OVF_CAP 4096
#define BSH     9                    // bucket = node >> 9 (512 nodes/bucket)
#define NB      196                  // ceil(100000/512)
#define BCAP    3072                 // per (rel,bucket) segment capacity
#define CHUNK   4096                 // edges per pass1 block
#define NCH     98                   // ceil(400000/4096)
#define PASS1_BLKS (NCH * N_RELS)    // 294
#define XH_BLKS 1024
#define MEGA_BLKS 782                // ceil(100000/128)

typedef _Float16 f16x8 __attribute__((ext_vector_type(8)));
typedef float    f32x4 __attribute__((ext_vector_type(4)));

static __device__ __forceinline__ ushort f2h(float f) {
    return __builtin_bit_cast(ushort, (_Float16)f);
}
static __device__ __forceinline__ float h_lo(uint u) {
    return __low2float(__builtin_bit_cast(__half2, u));
}
static __device__ __forceinline__ float h_hi(uint u) {
    return __high2float(__builtin_bit_cast(__half2, u));
}

// W transpose + fp16: Wt[r][j][k] = fp16(W[r][k][j]); bsum[j] = mean_r b[r][j]
__global__ void prep_w_kernel(const float* __restrict__ W, const float* __restrict__ b,
                              ushort* __restrict__ Wt, float* __restrict__ bsum) {
    int id = blockIdx.x * 256 + threadIdx.x;
    if (id < 3 * D * D) {
        int r = id >> 14;
        int rem = id & 16383;
        int k = rem >> 7, j = rem & 127;
        Wt[r * 16384 + j * 128 + k] = f2h(W[id]);
    }
    if (blockIdx.x == 0 && threadIdx.x < D) {
        int j = threadIdx.x;
        bsum[j] = (b[j] + b[D + j] + b[2 * D + j]) * (1.0f / 3.0f);
    }
}

// pass1: first PASS1_BLKS blocks bucket-partition edges (one global atomic per
// (block,bucket)); remaining XH_BLKS blocks convert x -> fp16 x_h (streaming).
__global__ __launch_bounds__(256) void pass1_kernel(
    const float* __restrict__ x, const int* __restrict__ edges,
    ushort* __restrict__ xh,
    int2* __restrict__ part_dst, int* __restrict__ part_src,
    int* __restrict__ gcur_dst, int* __restrict__ gcur_src) {
    __shared__ struct { int s[CHUNK]; int t[CHUNK]; } st;   // 32 KB
    __shared__ int histd[NB], hists[NB], segd[NB], segs[NB];
    const int bid = blockIdx.x;
    const int tid = threadIdx.x;

    if (bid < PASS1_BLKS) {
        const int rel   = bid / NCH;
        const int chunk = bid - rel * NCH;
        const int e0 = chunk * CHUNK;
        const int ne = min(CHUNK, N_EDGES - e0);
        const int* src = edges + (size_t)(rel * 2 + 0) * N_EDGES;
        const int* dst = edges + (size_t)(rel * 2 + 1) * N_EDGES;

        for (int i = tid; i < NB; i += 256) { histd[i] = 0; hists[i] = 0; }
        __syncthreads();
        for (int i = tid; i < ne; i += 256) {
            int s = src[e0 + i], t = dst[e0 + i];
            st.s[i] = s; st.t[i] = t;
            atomicAdd(&histd[t >> BSH], 1);
            atomicAdd(&hists[s >> BSH], 1);
        }
        __syncthreads();
        for (int i = tid; i < NB; i += 256) {
            int hd = histd[i];
            segd[i] = hd ? atomicAdd(&gcur_dst[rel * NB + i], hd) : 0;
            int hs = hists[i];
            segs[i] = hs ? atomicAdd(&gcur_src[rel * NB + i], hs) : 0;
            histd[i] = 0; hists[i] = 0;   // reuse as local cursors
        }
        __syncthreads();
        for (int i = tid; i < ne; i += 256) {
            int s = st.s[i], t = st.t[i];
            int bd = t >> BSH;
            int p = segd[bd] + atomicAdd(&histd[bd], 1);
            if (p < BCAP) part_dst[(size_t)(rel * NB + bd) * BCAP + p] = make_int2(s, t);
            int bs = s >> BSH;
            int q = segs[bs] + atomicAdd(&hists[bs], 1);
            if (q < BCAP) part_src[(size_t)(rel * NB + bs) * BCAP + q] = s;
        }
    } else {
        const int ngrp = N_NODES * D / 8;   // 1.6M groups of 8 floats
        for (int i = (bid - PASS1_BLKS) * 256 + tid; i < ngrp; i += XH_BLKS * 256) {
            const float4* xp = (const float4*)x + 2 * (size_t)i;
            float4 a = xp[0], bq = xp[1];
            uint4 v;
            v.x = (uint)f2h(a.x)  | ((uint)f2h(a.y)  << 16);
            v.y = (uint)f2h(a.z)  | ((uint)f2h(a.w)  << 16);
            v.z = (uint)f2h(bq.x) | ((uint)f2h(bq.y) << 16);
            v.w = (uint)f2h(bq.z) | ((uint)f2h(bq.w) << 16);
            ((uint4*)xh)[i] = v;
        }
    }
}

// pass2: per (bucket, rel) build 12-wide ELL + deg/rsqrt tables in LDS, write dense.
__global__ __launch_bounds__(256) void pass2_kernel(
    const int2* __restrict__ part_dst, const int* __restrict__ part_src,
    const int* __restrict__ gcur_dst, const int* __restrict__ gcur_src,
    int* __restrict__ ell, int* __restrict__ deg_in,
    float* __restrict__ rdi, float* __restrict__ rdo,
    int* __restrict__ ovf_cnt, int2* __restrict__ ovf) {
    __shared__ int cnt[512];
    __shared__ int lell[512 * ELL_W];   // 24 KB
    const int b = blockIdx.x, rel = blockIdx.y;
    const int tid = threadIdx.x;
    const int n0 = b << BSH;
    const int nvalid = min(512, N_NODES - n0);

    for (int i = tid; i < 512; i += 256) cnt[i] = 0;
    __syncthreads();
    const int m = min(gcur_dst[rel * NB + b], BCAP);
    const int2* pp = part_dst + (size_t)(rel * NB + b) * BCAP;
    for (int i = tid; i < m; i += 256) {
        int2 e = pp[i];
        int li = e.y - n0;
        int p = atomicAdd(&cnt[li], 1);
        if (p < ELL_W) lell[li * ELL_W + p] = e.x;
        else {
            int o = atomicAdd(ovf_cnt, 1);
            if (o < OVF_CAP) ovf[o] = make_int2(e.x, e.y | (rel << 20));
        }
    }
    __syncthreads();
    for (int i = tid; i < nvalid; i += 256) {
        int c = cnt[i];
        deg_in[rel * N_NODES + n0 + i] = c;
        rdi[rel * N_NODES + n0 + i] = rsqrtf((float)max(c, 1));
    }
    for (int i = tid; i < nvalid * ELL_W; i += 256)
        ell[(size_t)(rel * N_NODES + n0) * ELL_W + i] = lell[i];
    __syncthreads();
    for (int i = tid; i < 512; i += 256) cnt[i] = 0;
    __syncthreads();
    const int m2 = min(gcur_src[rel * NB + b], BCAP);
    const int* ps = part_src + (size_t)(rel * NB + b) * BCAP;
    for (int i = tid; i < m2; i += 256) atomicAdd(&cnt[ps[i] - n0], 1);
    __syncthreads();
    for (int i = tid; i < nvalid; i += 256)
        rdo[rel * N_NODES + n0 + i] = rsqrtf((float)max(cnt[i], 1));
}

// Mega: per 128-row tile, for each rel: aggregate agg = rdi * sum(rdo * xh[src])
// into a swizzled LDS fp16 tile (wave-local rows, no barriers), then
// MFMA agg @ Wt[rel] accumulating across rels. Epilogue: out = acc/3 + bsum.
__global__ __launch_bounds__(256) void mega_kernel(
    const ushort* __restrict__ xh, const ushort* __restrict__ Wt,
    const int* __restrict__ ell, const int* __restrict__ deg_in,
    const float* __restrict__ rdi, const float* __restrict__ rdo,
    const float* __restrict__ bsum, float* __restrict__ out) {
    __shared__ ushort agg[128 * 128];   // 32 KB, swizzled
    const int n0 = blockIdx.x * 128;
    const int tid = threadIdx.x;
    const int w = tid >> 6, l = tid & 63;
    const int wrow = w * 32;
    const int lr = l & 15, lk = (l >> 4) * 8;

    f32x4 acc[2][8];
    #pragma unroll
    for (int fi = 0; fi < 2; ++fi)
        #pragma unroll
        for (int fj = 0; fj < 8; ++fj)
            acc[fi][fj] = (f32x4){0.f, 0.f, 0.f, 0.f};

    for (int rel = 0; rel < 3; ++rel) {
        // --- aggregation into this wave's 32 rows ---
        for (int r32 = 0; r32 < 32; ++r32) {
            const int row = wrow + r32;
            const int n = n0 + row;
            const int base = rel * N_NODES + min(n, N_NODES - 1);
            const int cnt = (n < N_NODES) ? min(deg_in[base], ELL_W) : 0;
            int e = 0; float cl = 0.f;
            if (l < cnt) {
                e = ell[(size_t)base * ELL_W + l];
                cl = rdo[rel * N_NODES + e];
            }
            float ax = 0.f, ay = 0.f;
            int i = 0;
            for (; i + 2 <= cnt; i += 2) {
                int s0 = __shfl(e, i), s1 = __shfl(e, i + 1);
                float c0 = __shfl(cl, i), c1 = __shfl(cl, i + 1);
                uint u0 = *(const uint*)(xh + (size_t)s0 * 128 + 2 * l);
                uint u1 = *(const uint*)(xh + (size_t)s1 * 128 + 2 * l);
                ax = fmaf(h_lo(u0), c0, ax);
                ay = fmaf(h_hi(u0), c0, ay);
                ax = fmaf(h_lo(u1), c1, ax);
                ay = fmaf(h_hi(u1), c1, ay);
            }
            if (i < cnt) {
                int s0 = __shfl(e, i);
                float c0 = __shfl(cl, i);
                uint u0 = *(const uint*)(xh + (size_t)s0 * 128 + 2 * l);
                ax = fmaf(h_lo(u0), c0, ax);
                ay = fmaf(h_hi(u0), c0, ay);
            }
            float rv = rdi[base];
            if (n >= N_NODES) rv = 0.f;
            ax *= rv; ay *= rv;
            uint pk = (uint)f2h(ax) | ((uint)f2h(ay) << 16);
            int ba = (row * 256 + 4 * l) ^ ((row & 7) << 4);
            *(uint*)((char*)agg + ba) = pk;
        }
        // --- MFMA: own 32 rows x Wt[rel] (B-frags straight from global) ---
        const ushort* Wg = Wt + rel * 16384;
        #pragma unroll
        for (int ks = 0; ks < 4; ++ks) {
            f16x8 bfr[8];
            #pragma unroll
            for (int fj = 0; fj < 8; ++fj) {
                int j = fj * 16 + lr;
                bfr[fj] = *(const f16x8*)(Wg + j * 128 + ks * 32 + lk);
            }
            f16x8 afr[2];
            #pragma unroll
            for (int fi = 0; fi < 2; ++fi) {
                int row = wrow + fi * 16 + lr;
                int ba = (row * 256 + (ks * 32 + lk) * 2) ^ ((row & 7) << 4);
                afr[fi] = *(f16x8*)((char*)agg + ba);
            }
            #pragma unroll
            for (int fi = 0; fi < 2; ++fi)
                #pragma unroll
                for (int fj = 0; fj < 8; ++fj)
                    acc[fi][fj] = __builtin_amdgcn_mfma_f32_16x16x32_f16(
                        afr[fi], bfr[fj], acc[fi][fj], 0, 0, 0);
        }
    }

    // epilogue: C/D col = lane&15 (+fj*16), row = (lane>>4)*4 + i
    const int cr4 = (l >> 4) * 4;
    #pragma unroll
    for (int fi = 0; fi < 2; ++fi) {
        int rbase = n0 + wrow + fi * 16 + cr4;
        #pragma unroll
        for (int fj = 0; fj < 8; ++fj) {
            int col = fj * 16 + lr;
            float bs = bsum[col];
            #pragma unroll
            for (int i = 0; i < 4; ++i) {
                int row = rbase + i;
                if (row < N_NODES)
                    out[(size_t)row * 128 + col] = acc[fi][fj][i] * (1.f / 3.f) + bs;
            }
        }
    }
}

// Rare path (in-degree > 12): per-edge matvec xh[s] @ Wt[r], atomic add into out.
__global__ void ovf_kernel(const ushort* __restrict__ xh, const ushort* __restrict__ Wt,
                           const float* __restrict__ rdi, const float* __restrict__ rdo,
                           const int* __restrict__ ovf_cnt, const int2* __restrict__ ovf,
                           float* out) {
    int m = min(*ovf_cnt, OVF_CAP);
    int wid = (blockIdx.x * blockDim.x + threadIdx.x) >> 6;
    int l = threadIdx.x & 63;
    int nw = (gridDim.x * blockDim.x) >> 6;
    for (int ent = wid; ent < m; ent += nw) {
        int s = ovf[ent].x;
        int packed = ovf[ent].y;
        int t = packed & 0xFFFFF, r = packed >> 20;
        uint myx = *(const uint*)(xh + (size_t)s * 128 + 2 * l);
        const ushort* w0 = Wt + r * 16384 + (2 * l) * 128;
        const ushort* w1 = w0 + 128;
        float a0 = 0.f, a1 = 0.f;
        for (int kk = 0; kk < 64; ++kk) {
            uint xu = __shfl(myx, kk);
            float x0 = h_lo(xu), x1 = h_hi(xu);
            uint wa = *(const uint*)(w0 + 2 * kk);
            uint wb = *(const uint*)(w1 + 2 * kk);
            a0 += x0 * h_lo(wa) + x1 * h_hi(wa);
            a1 += x0 * h_lo(wb) + x1 * h_hi(wb);
        }
        float sc = rdo[r * N_NODES + s] * rdi[r * N_NODES + t] * (1.f / 3.f);
        atomicAdd(out + (size_t)t * 128 + 2 * l + 0, a0 * sc);
        atomicAdd(out + (size_t)t * 128 + 2 * l + 1, a1 * sc);
    }
}

extern "C" void kernel_launch(void* const* d_in, const int* in_sizes, int n_in,
                              void* d_out, int out_size, void* d_ws, size_t ws_size,
                              hipStream_t stream) {
    const float* x     = (const float*)d_in[0];
    const int*   edges = (const int*)d_in[1];   // [R][2][E] int32
    const float* W     = (const float*)d_in[2]; // [R][D][D]
    const float* b     = (const float*)d_in[3]; // [R][D]
    float* out = (float*)d_out;

    char* ws = (char*)d_ws;
    size_t off = 0;
    auto alloc = [&](size_t bytes) -> void* {
        void* p = ws + off;
        off += (bytes + 255) & ~(size_t)255;
        return p;
    };
    int*   gcur_dst = (int*)alloc((size_t)N_RELS * NB * 4);
    int*   gcur_src = (int*)alloc((size_t)N_RELS * NB * 4);
    int*   ovf_cnt  = (int*)alloc(256);
    size_t zero_bytes = off;                    // memset the three above
    float* bsum     = (float*)alloc((size_t)D * 4);
    ushort* Wt      = (ushort*)alloc((size_t)3 * D * D * 2);
    int2*  ovf      = (int2*)alloc((size_t)OVF_CAP * 8);
    int2*  part_dst = (int2*)alloc((size_t)N_RELS * NB * BCAP * 8);   // 13.8 MB
    int*   part_src = (int*)alloc((size_t)N_RELS * NB * BCAP * 4);    //  6.9 MB
    int*   ell      = (int*)alloc((size_t)NTOT * ELL_W * 4);          // 14.4 MB
    int*   deg_in   = (int*)alloc((size_t)NTOT * 4);
    float* rdi      = (float*)alloc((size_t)NTOT * 4);
    float* rdo      = (float*)alloc((size_t)NTOT * 4);
    ushort* xh      = (ushort*)alloc((size_t)N_NODES * D * 2);        // 25.6 MB

    hipMemsetAsync(ws, 0, zero_bytes, stream);
    prep_w_kernel<<<192, 256, 0, stream>>>(W, b, Wt, bsum);
    pass1_kernel<<<PASS1_BLKS + XH_BLKS, 256, 0, stream>>>(
        x, edges, xh, part_dst, part_src, gcur_dst, gcur_src);
    pass2_kernel<<<dim3(NB, 3), 256, 0, stream>>>(
        part_dst, part_src, gcur_dst, gcur_src, ell, deg_in, rdi, rdo, ovf_cnt, ovf);
    mega_kernel<<<MEGA_BLKS, 256, 0, stream>>>(
        xh, Wt, ell, deg_in, rdi, rdo, bsum, out);
    ovf_kernel<<<16, 256, 0, stream>>>(xh, Wt, rdi, rdo, ovf_cnt, ovf, out);
}

// Round 10
// 176.288 us; speedup vs baseline: 2.4335x; 2.4335x over previous
//
#include <hip/hip_runtime.h>
#include <hip/hip_fp16.h>
#include <math.h>

#define N_NODES 100000
#define N_RELS  3
#define N_EDGES 400000
#define D       128
#define NTOT    (N_RELS * N_NODES)   // 300000
#define ELL_W   12
#define OVF_CAP 4096
#define BSH     9                    // bucket = node >> 9 (512 nodes/bucket)
#define NB      196                  // ceil(100000/512)
#define BCAP    3072                 // per (rel,bucket) segment capacity
#define CHUNK   4096                 // edges per pass1 block
#define NCH     98                   // ceil(400000/4096)
#define PASS1_BLKS (NCH * N_RELS)    // 294
#define XH_BLKS 1024
#define GEMM_BLKS 782                // ceil(100000/128)

typedef _Float16 f16x8 __attribute__((ext_vector_type(8)));
typedef float    f32x4 __attribute__((ext_vector_type(4)));

static __device__ __forceinline__ ushort f2h(float f) {
    return __builtin_bit_cast(ushort, (_Float16)f);
}
static __device__ __forceinline__ float h_lo(uint u) {
    return __low2float(__builtin_bit_cast(__half2, u));
}
static __device__ __forceinline__ float h_hi(uint u) {
    return __high2float(__builtin_bit_cast(__half2, u));
}

// W transpose + fp16: Wt[r][j][k] = fp16(W[r][k][j]); bsum[j] = mean_r b[r][j]
__global__ void prep_w_kernel(const float* __restrict__ W, const float* __restrict__ b,
                              ushort* __restrict__ Wt, float* __restrict__ bsum) {
    int id = blockIdx.x * 256 + threadIdx.x;
    if (id < 3 * D * D) {
        int r = id >> 14;
        int rem = id & 16383;
        int k = rem >> 7, j = rem & 127;
        Wt[r * 16384 + j * 128 + k] = f2h(W[id]);
    }
    if (blockIdx.x == 0 && threadIdx.x < D) {
        int j = threadIdx.x;
        bsum[j] = (b[j] + b[D + j] + b[2 * D + j]) * (1.0f / 3.0f);
    }
}

// pass1: first PASS1_BLKS blocks bucket-partition edges (dst side packed as
// (s<<9)|li, src side as s), one global atomic per (block,bucket);
// remaining XH_BLKS blocks convert x -> fp16 x_h (streaming).
__global__ __launch_bounds__(256) void pass1_kernel(
    const float* __restrict__ x, const int* __restrict__ edges,
    ushort* __restrict__ xh,
    int* __restrict__ part_dst, int* __restrict__ part_src,
    int* __restrict__ gcur_dst, int* __restrict__ gcur_src) {
    __shared__ struct { int s[CHUNK]; int t[CHUNK]; } st;   // 32 KB
    __shared__ int histd[NB], hists[NB], segd[NB], segs[NB];
    const int bid = blockIdx.x;
    const int tid = threadIdx.x;

    if (bid < PASS1_BLKS) {
        const int rel   = bid / NCH;
        const int chunk = bid - rel * NCH;
        const int e0 = chunk * CHUNK;
        const int ne = min(CHUNK, N_EDGES - e0);
        const int* src = edges + (size_t)(rel * 2 + 0) * N_EDGES;
        const int* dst = edges + (size_t)(rel * 2 + 1) * N_EDGES;

        for (int i = tid; i < NB; i += 256) { histd[i] = 0; hists[i] = 0; }
        __syncthreads();
        for (int i = tid; i < ne; i += 256) {
            int s = src[e0 + i], t = dst[e0 + i];
            st.s[i] = s; st.t[i] = t;
            atomicAdd(&histd[t >> BSH], 1);
            atomicAdd(&hists[s >> BSH], 1);
        }
        __syncthreads();
        for (int i = tid; i < NB; i += 256) {
            int hd = histd[i];
            segd[i] = hd ? atomicAdd(&gcur_dst[rel * NB + i], hd) : 0;
            int hs = hists[i];
            segs[i] = hs ? atomicAdd(&gcur_src[rel * NB + i], hs) : 0;
            histd[i] = 0; hists[i] = 0;   // reuse as local cursors
        }
        __syncthreads();
        for (int i = tid; i < ne; i += 256) {
            int s = st.s[i], t = st.t[i];
            int bd = t >> BSH;
            int p = segd[bd] + atomicAdd(&histd[bd], 1);
            if (p < BCAP)
                part_dst[(size_t)(rel * NB + bd) * BCAP + p] = (s << 9) | (t & 511);
            int bs = s >> BSH;
            int q = segs[bs] + atomicAdd(&hists[bs], 1);
            if (q < BCAP) part_src[(size_t)(rel * NB + bs) * BCAP + q] = s;
        }
    } else {
        const int ngrp = N_NODES * D / 8;   // 1.6M groups of 8 floats
        for (int i = (bid - PASS1_BLKS) * 256 + tid; i < ngrp; i += XH_BLKS * 256) {
            const float4* xp = (const float4*)x + 2 * (size_t)i;
            float4 a = xp[0], bq = xp[1];
            uint4 v;
            v.x = (uint)f2h(a.x)  | ((uint)f2h(a.y)  << 16);
            v.y = (uint)f2h(a.z)  | ((uint)f2h(a.w)  << 16);
            v.z = (uint)f2h(bq.x) | ((uint)f2h(bq.y) << 16);
            v.w = (uint)f2h(bq.z) | ((uint)f2h(bq.w) << 16);
            ((uint4*)xh)[i] = v;
        }
    }
}

// pass2a: rdo table (out-degree rsqrt) from src-partition, per (bucket,rel).
__global__ __launch_bounds__(256) void pass2a_kernel(
    const int* __restrict__ part_src, const int* __restrict__ gcur_src,
    float* __restrict__ rdo) {
    __shared__ int cnt[512];
    const int b = blockIdx.x, rel = blockIdx.y;
    const int tid = threadIdx.x;
    const int n0 = b << BSH;
    const int nvalid = min(512, N_NODES - n0);
    for (int i = tid; i < 512; i += 256) cnt[i] = 0;
    __syncthreads();
    const int m = min(gcur_src[rel * NB + b], BCAP);
    const int* ps = part_src + (size_t)(rel * NB + b) * BCAP;
    for (int i = tid; i < m; i += 256) atomicAdd(&cnt[ps[i] & 511], 1);
    __syncthreads();
    for (int i = tid; i < nvalid; i += 256)
        rdo[rel * N_NODES + n0 + i] = rsqrtf((float)max(cnt[i], 1));
}

// agg: per (bucket, rel), 512 threads. Build lell[512][12] + cnt in LDS from
// dst-partition (ELL never hits global), then 8 waves aggregate 64 nodes each:
// agg[rel][n][:] = fp16( rdi_n * sum_e rdo[src_e] * xh[src_e][:] ).
__global__ __launch_bounds__(512) void agg_kernel(
    const int* __restrict__ part_dst, const int* __restrict__ gcur_dst,
    const ushort* __restrict__ xh, const float* __restrict__ rdo,
    float* __restrict__ rdi, ushort* __restrict__ agg,
    int* __restrict__ ovf_cnt, int2* __restrict__ ovf) {
    __shared__ int cnt[512];
    __shared__ int lell[512 * ELL_W];   // 24 KB
    const int b = blockIdx.x, rel = blockIdx.y;
    const int tid = threadIdx.x;
    const int n0 = b << BSH;
    const int nvalid = min(512, N_NODES - n0);

    cnt[tid] = 0;
    __syncthreads();
    const int m = min(gcur_dst[rel * NB + b], BCAP);
    const int* pp = part_dst + (size_t)(rel * NB + b) * BCAP;
    for (int i = tid; i < m; i += 512) {
        int pd = pp[i];
        int s = ((unsigned)pd) >> 9;
        int li = pd & 511;
        int p = atomicAdd(&cnt[li], 1);
        if (p < ELL_W) lell[li * ELL_W + p] = s;
        else {
            int o = atomicAdd(ovf_cnt, 1);
            if (o < OVF_CAP) ovf[o] = make_int2(s, (n0 + li) | (rel << 20));
        }
    }
    __syncthreads();
    if (tid < nvalid)
        rdi[rel * N_NODES + n0 + tid] = rsqrtf((float)max(cnt[tid], 1));

    const int w = tid >> 6, l = tid & 63;
    for (int it = 0; it < 64; ++it) {
        int li = w * 64 + it;
        int n = n0 + li;
        if (n >= N_NODES) break;
        int full = cnt[li];                 // wave-uniform LDS broadcast
        int c = min(full, ELL_W);
        int e = 0; float cl = 0.f;
        if (l < c) {
            e = lell[li * ELL_W + l];
            cl = rdo[rel * N_NODES + e];    // 1.2 MB table, L2-resident
        }
        float ax = 0.f, ay = 0.f;
        int i = 0;
        for (; i + 2 <= c; i += 2) {
            int s0 = __shfl(e, i), s1 = __shfl(e, i + 1);
            float c0 = __shfl(cl, i), c1 = __shfl(cl, i + 1);
            uint u0 = *(const uint*)(xh + (size_t)s0 * 128 + 2 * l);
            uint u1 = *(const uint*)(xh + (size_t)s1 * 128 + 2 * l);
            ax = fmaf(h_lo(u0), c0, ax);
            ay = fmaf(h_hi(u0), c0, ay);
            ax = fmaf(h_lo(u1), c1, ax);
            ay = fmaf(h_hi(u1), c1, ay);
        }
        if (i < c) {
            int s0 = __shfl(e, i);
            float c0 = __shfl(cl, i);
            uint u0 = *(const uint*)(xh + (size_t)s0 * 128 + 2 * l);
            ax = fmaf(h_lo(u0), c0, ax);
            ay = fmaf(h_hi(u0), c0, ay);
        }
        float rv = rsqrtf((float)max(full, 1));
        ax *= rv; ay *= rv;
        uint pk = (uint)f2h(ax) | ((uint)f2h(ay) << 16);
        *(uint*)(agg + ((size_t)rel * N_NODES + n) * 128 + 2 * l) = pk;
    }
}

// gemm: out[n][:] = (1/3) sum_r agg_r[n] @ Wt_r + bsum. 128-row tiles,
// acc accumulates across rels; W staged per rel in swizzled LDS.
__global__ __launch_bounds__(256) void gemm_kernel(
    const ushort* __restrict__ agg, const ushort* __restrict__ Wt,
    const float* __restrict__ bsum, float* __restrict__ out) {
    __shared__ ushort Bt[128 * 128];   // 32 KB
    const int n0 = blockIdx.x * 128;
    const int tid = threadIdx.x;
    const int w = tid >> 6, l = tid & 63;
    const int wrow = w * 32;
    const int lr = l & 15, lk = (l >> 4) * 8;

    f32x4 acc[2][8];
    #pragma unroll
    for (int fi = 0; fi < 2; ++fi)
        #pragma unroll
        for (int fj = 0; fj < 8; ++fj)
            acc[fi][fj] = (f32x4){0.f, 0.f, 0.f, 0.f};

    for (int rel = 0; rel < 3; ++rel) {
        __syncthreads();
        {
            const ushort* Wg = Wt + rel * 16384;
            #pragma unroll
            for (int c = 0; c < 8; ++c) {
                int id = c * 256 + tid;
                int j = id >> 4, k8 = id & 15;
                uint4 v = *(const uint4*)(Wg + j * 128 + k8 * 8);
                int ba = (j * 256 + k8 * 16) ^ ((j & 7) << 4);
                *(uint4*)((char*)Bt + ba) = v;
            }
        }
        __syncthreads();

        f16x8 a[2][4];
        #pragma unroll
        for (int fi = 0; fi < 2; ++fi) {
            int row = min(n0 + wrow + fi * 16 + lr, N_NODES - 1);
            const ushort* ap = agg + ((size_t)rel * N_NODES + row) * 128 + lk;
            #pragma unroll
            for (int ks = 0; ks < 4; ++ks)
                a[fi][ks] = *(const f16x8*)(ap + ks * 32);
        }

        #pragma unroll
        for (int ks = 0; ks < 4; ++ks) {
            f16x8 bfr[8];
            #pragma unroll
            for (int fj = 0; fj < 8; ++fj) {
                int j = fj * 16 + lr;
                int ba = (j * 256 + (ks * 32 + lk) * 2) ^ ((j & 7) << 4);
                bfr[fj] = *(f16x8*)((char*)Bt + ba);
            }
            #pragma unroll
            for (int fi = 0; fi < 2; ++fi)
                #pragma unroll
                for (int fj = 0; fj < 8; ++fj)
                    acc[fi][fj] = __builtin_amdgcn_mfma_f32_16x16x32_f16(
                        a[fi][ks], bfr[fj], acc[fi][fj], 0, 0, 0);
        }
    }

    // epilogue: C/D col = lane&15 (+fj*16), row = (lane>>4)*4 + i
    const int cr4 = (l >> 4) * 4;
    #pragma unroll
    for (int fi = 0; fi < 2; ++fi) {
        int rbase = n0 + wrow + fi * 16 + cr4;
        #pragma unroll
        for (int fj = 0; fj < 8; ++fj) {
            int col = fj * 16 + lr;
            float bs = bsum[col];
            #pragma unroll
            for (int i = 0; i < 4; ++i) {
                int row = rbase + i;
                if (row < N_NODES)
                    out[(size_t)row * 128 + col] = acc[fi][fj][i] * (1.f / 3.f) + bs;
            }
        }
    }
}

// Rare path (in-degree > 12): per-edge matvec xh[s] @ Wt[r], atomic add into out.
__global__ void ovf_kernel(const ushort* __restrict__ xh, const ushort* __restrict__ Wt,
                           const float* __restrict__ rdi, const float* __restrict__ rdo,
                           const int* __restrict__ ovf_cnt, const int2* __restrict__ ovf,
                           float* out) {
    int m = min(*ovf_cnt, OVF_CAP);
    int wid = (blockIdx.x * blockDim.x + threadIdx.x) >> 6;
    int l = threadIdx.x & 63;
    int nw = (gridDim.x * blockDim.x) >> 6;
    for (int ent = wid; ent < m; ent += nw) {
        int s = ovf[ent].x;
        int packed = ovf[ent].y;
        int t = packed & 0xFFFFF, r = packed >> 20;
        uint myx = *(const uint*)(xh + (size_t)s * 128 + 2 * l);
        const ushort* w0 = Wt + r * 16384 + (2 * l) * 128;
        const ushort* w1 = w0 + 128;
        float a0 = 0.f, a1 = 0.f;
        for (int kk = 0; kk < 64; ++kk) {
            uint xu = __shfl(myx, kk);
            float x0 = h_lo(xu), x1 = h_hi(xu);
            uint wa = *(const uint*)(w0 + 2 * kk);
            uint wb = *(const uint*)(w1 + 2 * kk);
            a0 += x0 * h_lo(wa) + x1 * h_hi(wa);
            a1 += x0 * h_lo(wb) + x1 * h_hi(wb);
        }
        float sc = rdo[r * N_NODES + s] * rdi[r * N_NODES + t] * (1.f / 3.f);
        atomicAdd(out + (size_t)t * 128 + 2 * l + 0, a0 * sc);
        atomicAdd(out + (size_t)t * 128 + 2 * l + 1, a1 * sc);
    }
}

extern "C" void kernel_launch(void* const* d_in, const int* in_sizes, int n_in,
                              void* d_out, int out_size, void* d_ws, size_t ws_size,
                              hipStream_t stream) {
    const float* x     = (const float*)d_in[0];
    const int*   edges = (const int*)d_in[1];   // [R][2][E] int32
    const float* W     = (const float*)d_in[2]; // [R][D][D]
    const float* b     = (const float*)d_in[3]; // [R][D]
    float* out = (float*)d_out;

    char* ws = (char*)d_ws;
    size_t off = 0;
    auto alloc = [&](size_t bytes) -> void* {
        void* p = ws + off;
        off += (bytes + 255) & ~(size_t)255;
        return p;
    };
    int*   gcur_dst = (int*)alloc((size_t)N_RELS * NB * 4);
    int*   gcur_src = (int*)alloc((size_t)N_RELS * NB * 4);
    int*   ovf_cnt  = (int*)alloc(256);
    size_t zero_bytes = off;                    // memset the three above
    float* bsum     = (float*)alloc((size_t)D * 4);
    ushort* Wt      = (ushort*)alloc((size_t)3 * D * D * 2);
    int2*  ovf      = (int2*)alloc((size_t)OVF_CAP * 8);
    int*   part_dst = (int*)alloc((size_t)N_RELS * NB * BCAP * 4);    // 6.9 MB
    int*   part_src = (int*)alloc((size_t)N_RELS * NB * BCAP * 4);    // 6.9 MB
    float* rdi      = (float*)alloc((size_t)NTOT * 4);
    float* rdo      = (float*)alloc((size_t)NTOT * 4);
    ushort* xh      = (ushort*)alloc((size_t)N_NODES * D * 2);        // 25.6 MB
    ushort* agg     = (ushort*)alloc((size_t)N_RELS * N_NODES * D * 2); // 76.8 MB

    hipMemsetAsync(ws, 0, zero_bytes, stream);
    prep_w_kernel<<<192, 256, 0, stream>>>(W, b, Wt, bsum);
    pass1_kernel<<<PASS1_BLKS + XH_BLKS, 256, 0, stream>>>(
        x, edges, xh, part_dst, part_src, gcur_dst, gcur_src);
    pass2a_kernel<<<dim3(NB, 3), 256, 0, stream>>>(part_src, gcur_src, rdo);
    agg_kernel<<<dim3(NB, 3), 512, 0, stream>>>(
        part_dst, gcur_dst, xh, rdo, rdi, agg, ovf_cnt, ovf);
    gemm_kernel<<<GEMM_BLKS, 256, 0, stream>>>(agg, Wt, bsum, out);
    ovf_kernel<<<16, 256, 0, stream>>>(xh, Wt, rdi, rdo, ovf_cnt, ovf, out);
}